// Round 1
// baseline (15968.480 us; speedup 1.0000x reference)
//
#include <hip/hip_runtime.h>
#include <cmath>

// GCN: 3 layers of (dense GEMM -> edge scatter-add SpMM -> bias (+leaky)) + log_softmax
// Dims: NFEAT=512, NHID1=16, NHID2=64, NCLASS=16

// ---------------- GEMM: Y[N,C] = X[N,K] @ W[K,C] --------------------------
// Thread-per-row. X row read as float4 (coalesced-ish, rows streamed once).
// W indexed by wave-uniform (k,c) -> compiler emits scalar loads (W <= 32 KB).
template<int K, int C>
__global__ __launch_bounds__(256) void gemm_rows(const float* __restrict__ X,
                                                 const float* __restrict__ W,
                                                 float* __restrict__ Y, int N) {
    int row = blockIdx.x * 256 + threadIdx.x;
    if (row >= N) return;
    float acc[C];
#pragma unroll
    for (int c = 0; c < C; ++c) acc[c] = 0.f;
    const float4* Xv = reinterpret_cast<const float4*>(X + (size_t)row * K);
    for (int k0 = 0; k0 < K; k0 += 4) {
        float4 xv = Xv[k0 / 4];
        const float xs[4] = {xv.x, xv.y, xv.z, xv.w};
#pragma unroll
        for (int kk = 0; kk < 4; ++kk) {
#pragma unroll
            for (int c = 0; c < C; ++c)
                acc[c] += xs[kk] * W[(size_t)(k0 + kk) * C + c];
        }
    }
    float4* Yv = reinterpret_cast<float4*>(Y + (size_t)row * C);
#pragma unroll
    for (int q = 0; q < C / 4; ++q)
        Yv[q] = make_float4(acc[4*q], acc[4*q+1], acc[4*q+2], acc[4*q+3]);
}

// ---------------- agg init: A[n,c] = b[c] ---------------------------------
template<int C>
__global__ __launch_bounds__(256) void init_bias(float* __restrict__ A,
                                                 const float* __restrict__ b, int n) {
    int i = blockIdx.x * 256 + threadIdx.x;
    if (i < n) A[i] = b[i & (C - 1)];
}

// ---------------- edge scatter: A[dst] += ev * S[src] ---------------------
template<int C>
__global__ __launch_bounds__(256) void scatter_edges(const int* __restrict__ src,
                                                     const int* __restrict__ dst,
                                                     const float* __restrict__ ev,
                                                     const float* __restrict__ S,
                                                     float* __restrict__ A, int E) {
    int e = blockIdx.x * 256 + threadIdx.x;
    if (e >= E) return;
    int s = src[e], d = dst[e];
    float v = ev[e];
    const float4* Sv = reinterpret_cast<const float4*>(S + (size_t)s * C);
    float* Ad = A + (size_t)d * C;
#pragma unroll
    for (int q = 0; q < C / 4; ++q) {
        float4 m = Sv[q];
        atomicAdd(Ad + 4*q + 0, v * m.x);
        atomicAdd(Ad + 4*q + 1, v * m.y);
        atomicAdd(Ad + 4*q + 2, v * m.z);
        atomicAdd(Ad + 4*q + 3, v * m.w);
    }
}

// ---------------- leaky relu elementwise ----------------------------------
__global__ __launch_bounds__(256) void leaky_k(float* __restrict__ H,
                                               const float* __restrict__ A, int n) {
    int i = blockIdx.x * 256 + threadIdx.x;
    if (i < n) {
        float x = A[i];
        H[i] = x > 0.f ? x : 0.01f * x;
    }
}

// ---------------- row log_softmax over C=16 -------------------------------
__global__ __launch_bounds__(256) void logsoftmax16(const float* __restrict__ A,
                                                    float* __restrict__ out, int N) {
    int r = blockIdx.x * 256 + threadIdx.x;
    if (r >= N) return;
    float v[16];
    const float4* Av = reinterpret_cast<const float4*>(A + (size_t)r * 16);
#pragma unroll
    for (int q = 0; q < 4; ++q) {
        float4 t = Av[q];
        v[4*q] = t.x; v[4*q+1] = t.y; v[4*q+2] = t.z; v[4*q+3] = t.w;
    }
    float m = v[0];
#pragma unroll
    for (int c = 1; c < 16; ++c) m = fmaxf(m, v[c]);
    float ssum = 0.f;
#pragma unroll
    for (int c = 0; c < 16; ++c) ssum += __expf(v[c] - m);
    float lse = m + __logf(ssum);
    float4* Ov = reinterpret_cast<float4*>(out + (size_t)r * 16);
#pragma unroll
    for (int q = 0; q < 4; ++q)
        Ov[q] = make_float4(v[4*q] - lse, v[4*q+1] - lse, v[4*q+2] - lse, v[4*q+3] - lse);
}

extern "C" void kernel_launch(void* const* d_in, const int* in_sizes, int n_in,
                              void* d_out, int out_size, void* d_ws, size_t ws_size,
                              hipStream_t stream) {
    const float* x   = (const float*)d_in[0];
    const int*   src = (const int*)d_in[1];
    const int*   dst = (const int*)d_in[2];
    const float* ev  = (const float*)d_in[3];
    const float* W1  = (const float*)d_in[4];
    const float* b1  = (const float*)d_in[5];
    const float* W2  = (const float*)d_in[6];
    const float* b2  = (const float*)d_in[7];
    const float* W3  = (const float*)d_in[8];
    const float* b3  = (const float*)d_in[9];
    float* out = (float*)d_out;

    const int N = in_sizes[0] / 512;   // 100000
    const int E = in_sizes[1];         // 3200000

    float* sup = (float*)d_ws;                     // N x 64 max
    float* agg = sup + (size_t)N * 64;             // N x 64 max
    float* h   = agg + (size_t)N * 64;             // N x 64 max

    auto blks = [](long n) { return (int)((n + 255) / 256); };

    // ---- layer 1: x[N,512] @ W1[512,16] -> spmm -> +b1, leaky ----
    gemm_rows<512, 16><<<blks(N), 256, 0, stream>>>(x, W1, sup, N);
    init_bias<16><<<blks((long)N * 16), 256, 0, stream>>>(agg, b1, N * 16);
    scatter_edges<16><<<blks(E), 256, 0, stream>>>(src, dst, ev, sup, agg, E);
    leaky_k<<<blks((long)N * 16), 256, 0, stream>>>(h, agg, N * 16);

    // ---- layer 2: h[N,16] @ W2[16,64] ----
    gemm_rows<16, 64><<<blks(N), 256, 0, stream>>>(h, W2, sup, N);
    init_bias<64><<<blks((long)N * 64), 256, 0, stream>>>(agg, b2, N * 64);
    scatter_edges<64><<<blks(E), 256, 0, stream>>>(src, dst, ev, sup, agg, E);
    leaky_k<<<blks((long)N * 64), 256, 0, stream>>>(h, agg, N * 64);

    // ---- layer 3: h[N,64] @ W3[64,16] -> spmm -> +b3 -> log_softmax ----
    gemm_rows<64, 16><<<blks(N), 256, 0, stream>>>(h, W3, sup, N);
    init_bias<16><<<blks((long)N * 16), 256, 0, stream>>>(agg, b3, N * 16);
    scatter_edges<16><<<blks(E), 256, 0, stream>>>(src, dst, ev, sup, agg, E);
    logsoftmax16<<<blks(N), 256, 0, stream>>>(agg, out, N);
}

// Round 2
// 985.726 us; speedup vs baseline: 16.1997x; 16.1997x over previous
//
#include <hip/hip_runtime.h>
#include <cmath>

// GCN: 3 x (dense GEMM -> pull-SpMM(+bias+act)) + fused log_softmax.
// SpMM strategy: counting-sort edges by dst into CSR once per call (int
// atomics only), then one wave per destination node gathers & sums its
// incoming messages -- no fp32 atomics (those were write-through to HBM:
// 6.55 GB WRITE_SIZE, 10.6 ms for the C=64 layer in round 0).

// ---------------- GEMM: Y[N,C] = X[N,K] @ W[K,C] --------------------------
template<int K, int C>
__global__ __launch_bounds__(256) void gemm_rows(const float* __restrict__ X,
                                                 const float* __restrict__ W,
                                                 float* __restrict__ Y, int N) {
    int row = blockIdx.x * 256 + threadIdx.x;
    if (row >= N) return;
    float acc[C];
#pragma unroll
    for (int c = 0; c < C; ++c) acc[c] = 0.f;
    const float4* Xv = reinterpret_cast<const float4*>(X + (size_t)row * K);
    for (int k0 = 0; k0 < K; k0 += 4) {
        float4 xv = Xv[k0 / 4];
        const float xs[4] = {xv.x, xv.y, xv.z, xv.w};
#pragma unroll
        for (int kk = 0; kk < 4; ++kk) {
#pragma unroll
            for (int c = 0; c < C; ++c)
                acc[c] += xs[kk] * W[(size_t)(k0 + kk) * C + c];
        }
    }
    float4* Yv = reinterpret_cast<float4*>(Y + (size_t)row * C);
#pragma unroll
    for (int q = 0; q < C / 4; ++q)
        Yv[q] = make_float4(acc[4*q], acc[4*q+1], acc[4*q+2], acc[4*q+3]);
}

// ---------------- CSR build: histogram ------------------------------------
__global__ __launch_bounds__(256) void hist_k(const int* __restrict__ dst,
                                              int* __restrict__ cnt, int E) {
    int e = blockIdx.x * 256 + threadIdx.x;
    if (e < E) atomicAdd(&cnt[dst[e]], 1);
}

// ---------------- CSR build: single-block exclusive scan ------------------
// cnt (in) and cursor (out) may alias; off gets exclusive offsets, off[N]=total.
__global__ __launch_bounds__(1024) void scan_k(const int* __restrict__ cnt,
                                               int* __restrict__ off,
                                               int* __restrict__ cursor, int N) {
    __shared__ int sdata[1024];
    __shared__ int carry;
    if (threadIdx.x == 0) carry = 0;
    __syncthreads();
    for (int base = 0; base < N; base += 1024) {
        int i = base + (int)threadIdx.x;
        int v = (i < N) ? cnt[i] : 0;
        sdata[threadIdx.x] = v;
        __syncthreads();
        for (int s = 1; s < 1024; s <<= 1) {
            int t = (threadIdx.x >= (unsigned)s) ? sdata[threadIdx.x - s] : 0;
            __syncthreads();
            sdata[threadIdx.x] += t;
            __syncthreads();
        }
        int excl = sdata[threadIdx.x] - v + carry;
        if (i < N) { off[i] = excl; cursor[i] = excl; }
        __syncthreads();
        if (threadIdx.x == 1023) carry += sdata[1023];
        __syncthreads();
    }
    if (threadIdx.x == 0) off[N] = carry;
}

// ---------------- CSR build: scatter edges into slots ---------------------
__global__ __launch_bounds__(256) void fill_k(const int* __restrict__ src,
                                              const int* __restrict__ dst,
                                              const float* __restrict__ ev,
                                              int* __restrict__ cursor,
                                              int* __restrict__ ssrc,
                                              float* __restrict__ sev, int E) {
    int e = blockIdx.x * 256 + threadIdx.x;
    if (e >= E) return;
    int d = dst[e];
    int p = atomicAdd(&cursor[d], 1);
    ssrc[p] = src[e];
    sev[p] = ev[e];
}

// ---------------- pull-SpMM, C=64: one wave per node, lane=feature --------
__global__ __launch_bounds__(256) void pull64(const int* __restrict__ off,
                                              const int* __restrict__ ssrc,
                                              const float* __restrict__ sev,
                                              const float* __restrict__ S,
                                              const float* __restrict__ b,
                                              float* __restrict__ H, int N) {
    int wid = (blockIdx.x * 256 + (int)threadIdx.x) >> 6;
    int lane = threadIdx.x & 63;
    if (wid >= N) return;
    int e0 = off[wid], e1 = off[wid + 1];
    float acc = 0.f;
    int e = e0;
    for (; e + 1 < e1; e += 2) {
        int s0 = ssrc[e], s1 = ssrc[e + 1];
        float v0 = sev[e], v1 = sev[e + 1];
        float a0 = S[(size_t)s0 * 64 + lane];
        float a1 = S[(size_t)s1 * 64 + lane];
        acc += v0 * a0;
        acc += v1 * a1;
    }
    if (e < e1) acc += sev[e] * S[(size_t)ssrc[e] * 64 + lane];
    float x = acc + b[lane];
    H[(size_t)wid * 64 + lane] = x > 0.f ? x : 0.01f * x;
}

// ---------------- pull-SpMM, C=16: wave = 4 edge-groups x 16 features -----
// SOFTMAX=false: write leaky(acc+b); SOFTMAX=true: write log_softmax(acc+b).
template<bool SOFTMAX>
__global__ __launch_bounds__(256) void pull16(const int* __restrict__ off,
                                              const int* __restrict__ ssrc,
                                              const float* __restrict__ sev,
                                              const float* __restrict__ S,
                                              const float* __restrict__ b,
                                              float* __restrict__ O, int N) {
    int wid = (blockIdx.x * 256 + (int)threadIdx.x) >> 6;
    int lane = threadIdx.x & 63;
    if (wid >= N) return;
    int c = lane & 15, eg = lane >> 4;
    int e0 = off[wid], e1 = off[wid + 1];
    float acc = 0.f;
    for (int e = e0 + eg; e < e1; e += 4)
        acc += sev[e] * S[(size_t)ssrc[e] * 16 + c];
    // reduce across the 4 edge-groups (lane bits 4,5)
    acc += __shfl_xor(acc, 16);
    acc += __shfl_xor(acc, 32);
    float x = acc + b[c];
    if (!SOFTMAX) {
        if (lane < 16) O[(size_t)wid * 16 + c] = x > 0.f ? x : 0.01f * x;
    } else {
        float m = x;
#pragma unroll
        for (int s = 1; s < 16; s <<= 1) m = fmaxf(m, __shfl_xor(m, s));
        float ex = __expf(x - m), ssum = ex;
#pragma unroll
        for (int s = 1; s < 16; s <<= 1) ssum += __shfl_xor(ssum, s);
        float lse = m + __logf(ssum);
        if (lane < 16) O[(size_t)wid * 16 + c] = x - lse;
    }
}

extern "C" void kernel_launch(void* const* d_in, const int* in_sizes, int n_in,
                              void* d_out, int out_size, void* d_ws, size_t ws_size,
                              hipStream_t stream) {
    const float* x   = (const float*)d_in[0];
    const int*   src = (const int*)d_in[1];
    const int*   dst = (const int*)d_in[2];
    const float* ev  = (const float*)d_in[3];
    const float* W1  = (const float*)d_in[4];
    const float* b1  = (const float*)d_in[5];
    const float* W2  = (const float*)d_in[6];
    const float* b2  = (const float*)d_in[7];
    const float* W3  = (const float*)d_in[8];
    const float* b3  = (const float*)d_in[9];
    float* out = (float*)d_out;

    const int N = in_sizes[0] / 512;   // 100000
    const int E = in_sizes[1];         // 3200000

    // workspace layout
    float* sup    = (float*)d_ws;                   // N x 64 fp32 (gemm out / pull in)
    float* h      = sup + (size_t)N * 64;           // N x 64 fp32 (pull out / gemm in)
    float* sev    = h + (size_t)N * 64;             // E fp32 sorted edge vals
    int*   ssrc   = (int*)(sev + E);                // E int sorted srcs
    int*   off    = ssrc + E;                       // N+1 offsets
    int*   cursor = off + (N + 1);                  // N counters / cursors

    auto blks = [](long n) { return (int)((n + 255) / 256); };
    const int pull_blocks = blks((long)N * 64);     // 1 wave per node, 4 waves/block

    // ---- CSR build (counting sort by dst) ----
    hipMemsetAsync(cursor, 0, (size_t)N * 4, stream);
    hist_k<<<blks(E), 256, 0, stream>>>(dst, cursor, E);
    scan_k<<<1, 1024, 0, stream>>>(cursor, off, cursor, N);
    fill_k<<<blks(E), 256, 0, stream>>>(src, dst, ev, cursor, ssrc, sev, E);

    // ---- layer 1: x[N,512] @ W1 -> pull -> +b1, leaky ----
    gemm_rows<512, 16><<<blks(N), 256, 0, stream>>>(x, W1, sup, N);
    pull16<false><<<pull_blocks, 256, 0, stream>>>(off, ssrc, sev, sup, b1, h, N);

    // ---- layer 2: h[N,16] @ W2 -> pull -> +b2, leaky ----
    gemm_rows<16, 64><<<blks(N), 256, 0, stream>>>(h, W2, sup, N);
    pull64<<<pull_blocks, 256, 0, stream>>>(off, ssrc, sev, sup, b2, h, N);

    // ---- layer 3: h[N,64] @ W3 -> pull -> +b3 -> log_softmax ----
    gemm_rows<64, 16><<<blks(N), 256, 0, stream>>>(h, W3, sup, N);
    pull16<true><<<pull_blocks, 256, 0, stream>>>(off, ssrc, sev, sup, b3, out, N);
}

// Round 3
// 675.080 us; speedup vs baseline: 23.6542x; 1.4602x over previous
//
#include <hip/hip_runtime.h>
#include <cmath>

// GCN: 3 x (dense GEMM <-> pull-SpMM) + fused log_softmax.
// Key algebra: spmm(A, h@W) == spmm(A, h)@W, so every layer aggregates in
// the SMALLER dim (16 for all three layers here). CSR built per-call via
// counting sort (histogram+rank -> scan -> atomic-free fill of packed
// {src,ev} int2 records).

// ---------------- GEMM: Y[N,C] = X[N,K] @ W[K,C] (+opt bias+leaky) --------
template<int K, int C, int FUSE_BIAS_LEAKY>
__global__ __launch_bounds__(256) void gemm_rows(const float* __restrict__ X,
                                                 const float* __restrict__ W,
                                                 const float* __restrict__ b,
                                                 float* __restrict__ Y, int N) {
    int row = blockIdx.x * 256 + threadIdx.x;
    if (row >= N) return;
    float acc[C];
#pragma unroll
    for (int c = 0; c < C; ++c) acc[c] = 0.f;
    const float4* Xv = reinterpret_cast<const float4*>(X + (size_t)row * K);
    for (int k0 = 0; k0 < K; k0 += 4) {
        float4 xv = Xv[k0 / 4];
        const float xs[4] = {xv.x, xv.y, xv.z, xv.w};
#pragma unroll
        for (int kk = 0; kk < 4; ++kk) {
#pragma unroll
            for (int c = 0; c < C; ++c)
                acc[c] += xs[kk] * W[(size_t)(k0 + kk) * C + c];
        }
    }
#pragma unroll
    for (int c = 0; c < C; ++c) {
        float v = acc[c];
        if (FUSE_BIAS_LEAKY) {
            v += b[c];
            v = v > 0.f ? v : 0.01f * v;
        }
        acc[c] = v;
    }
    float4* Yv = reinterpret_cast<float4*>(Y + (size_t)row * C);
#pragma unroll
    for (int q = 0; q < C / 4; ++q)
        Yv[q] = make_float4(acc[4*q], acc[4*q+1], acc[4*q+2], acc[4*q+3]);
}

// ---------------- CSR build: histogram + per-edge rank --------------------
__global__ __launch_bounds__(256) void hist_rank_k(const int* __restrict__ dst,
                                                   int* __restrict__ cnt,
                                                   int* __restrict__ rank, int E) {
    int e = blockIdx.x * 256 + threadIdx.x;
    if (e < E) rank[e] = atomicAdd(&cnt[dst[e]], 1);
}

// ---------------- scan step A: per-block sums -----------------------------
__global__ __launch_bounds__(256) void block_sums_k(const int* __restrict__ cnt,
                                                    int* __restrict__ bsum, int N) {
    int i = blockIdx.x * 256 + threadIdx.x;
    int v = (i < N) ? cnt[i] : 0;
#pragma unroll
    for (int s = 1; s < 64; s <<= 1) v += __shfl_xor(v, s);
    __shared__ int ws[4];
    if ((threadIdx.x & 63) == 0) ws[threadIdx.x >> 6] = v;
    __syncthreads();
    if (threadIdx.x == 0) bsum[blockIdx.x] = ws[0] + ws[1] + ws[2] + ws[3];
}

// ---------------- scan step B: exclusive scan of block sums (NB<=512) -----
__global__ __launch_bounds__(512) void scan_bsums_k(int* __restrict__ bsum, int NB) {
    __shared__ int s[512];
    int v = ((int)threadIdx.x < NB) ? bsum[threadIdx.x] : 0;
    s[threadIdx.x] = v;
    __syncthreads();
    for (int st = 1; st < 512; st <<= 1) {
        int t = (threadIdx.x >= (unsigned)st) ? s[threadIdx.x - st] : 0;
        __syncthreads();
        s[threadIdx.x] += t;
        __syncthreads();
    }
    if ((int)threadIdx.x < NB) bsum[threadIdx.x] = s[threadIdx.x] - v;  // exclusive
}

// ---------------- scan step C: block-local scan + base -> off -------------
__global__ __launch_bounds__(256) void block_scan_write_k(const int* __restrict__ cnt,
                                                          const int* __restrict__ bsum,
                                                          int* __restrict__ off,
                                                          int N, int E) {
    int i = blockIdx.x * 256 + threadIdx.x;
    int v = (i < N) ? cnt[i] : 0;
    __shared__ int s[256];
    s[threadIdx.x] = v;
    __syncthreads();
    for (int st = 1; st < 256; st <<= 1) {
        int t = (threadIdx.x >= (unsigned)st) ? s[threadIdx.x - st] : 0;
        __syncthreads();
        s[threadIdx.x] += t;
        __syncthreads();
    }
    if (i < N) off[i] = s[threadIdx.x] - v + bsum[blockIdx.x];
    if (i == 0) off[N] = E;
}

// ---------------- CSR build: atomic-free fill of packed records -----------
__global__ __launch_bounds__(256) void fill_k(const int* __restrict__ src,
                                              const int* __restrict__ dst,
                                              const float* __restrict__ ev,
                                              const int* __restrict__ rank,
                                              const int* __restrict__ off,
                                              int2* __restrict__ edges, int E) {
    int e = blockIdx.x * 256 + threadIdx.x;
    if (e >= E) return;
    int p = off[dst[e]] + rank[e];
    edges[p] = make_int2(src[e], __float_as_int(ev[e]));
}

// ---------------- pull-SpMM, C=16: wave = 4 edge-groups x 16 features -----
// MODE: 0 plain sum, 1 +bias+leaky, 2 +bias+log_softmax
template<int MODE>
__global__ __launch_bounds__(256) void pull16(const int* __restrict__ off,
                                              const int2* __restrict__ edges,
                                              const float* __restrict__ S,
                                              const float* __restrict__ b,
                                              float* __restrict__ O, int N) {
    int wid = (blockIdx.x * 256 + (int)threadIdx.x) >> 6;
    int lane = threadIdx.x & 63;
    if (wid >= N) return;
    int c = lane & 15, eg = lane >> 4;
    int e0 = off[wid], e1 = off[wid + 1];
    float acc = 0.f;
    for (int e = e0 + eg; e < e1; e += 4) {
        int2 ed = edges[e];
        acc += __int_as_float(ed.y) * S[(size_t)ed.x * 16 + c];
    }
    // reduce across the 4 edge-groups (lane bits 4,5)
    acc += __shfl_xor(acc, 16);
    acc += __shfl_xor(acc, 32);
    if (MODE == 0) {
        if (lane < 16) O[(size_t)wid * 16 + c] = acc;
    } else if (MODE == 1) {
        float x = acc + b[c];
        if (lane < 16) O[(size_t)wid * 16 + c] = x > 0.f ? x : 0.01f * x;
    } else {
        float x = acc + b[c];
        float m = x;
#pragma unroll
        for (int s = 1; s < 16; s <<= 1) m = fmaxf(m, __shfl_xor(m, s));
        float ex = __expf(x - m), ssum = ex;
#pragma unroll
        for (int s = 1; s < 16; s <<= 1) ssum += __shfl_xor(ssum, s);
        float lse = m + __logf(ssum);
        if (lane < 16) O[(size_t)wid * 16 + c] = x - lse;
    }
}

extern "C" void kernel_launch(void* const* d_in, const int* in_sizes, int n_in,
                              void* d_out, int out_size, void* d_ws, size_t ws_size,
                              hipStream_t stream) {
    const float* x   = (const float*)d_in[0];
    const int*   src = (const int*)d_in[1];
    const int*   dst = (const int*)d_in[2];
    const float* ev  = (const float*)d_in[3];
    const float* W1  = (const float*)d_in[4];
    const float* b1  = (const float*)d_in[5];
    const float* W2  = (const float*)d_in[6];
    const float* b2  = (const float*)d_in[7];
    const float* W3  = (const float*)d_in[8];
    const float* b3  = (const float*)d_in[9];
    float* out = (float*)d_out;

    const int N = in_sizes[0] / 512;   // 100000
    const int E = in_sizes[1];         // 3200000

    // workspace layout (floats/ints, 4B units)
    float* sup   = (float*)d_ws;                    // N x 64 scratch A
    float* h     = sup + (size_t)N * 64;            // N x 64 scratch B
    int2*  edges = (int2*)(h + (size_t)N * 64);     // E packed {src, ev}
    int*   off   = (int*)(edges + E);               // N+1
    int*   cnt   = off + (N + 1);                   // N
    int*   bsum  = cnt + N;                         // num blocks (<=512)
    int*   rank  = (int*)sup;                       // E (aliases sup: dead until gemm1)

    auto blks = [](long n) { return (int)((n + 255) / 256); };
    const int NB = blks(N);                         // 391
    const int pull_blocks = blks((long)N * 64);     // 1 wave per node

    // ---- CSR build (counting sort by dst, atomic-free fill) ----
    hipMemsetAsync(cnt, 0, (size_t)N * 4, stream);
    hist_rank_k<<<blks(E), 256, 0, stream>>>(dst, cnt, rank, E);
    block_sums_k<<<NB, 256, 0, stream>>>(cnt, bsum, N);
    scan_bsums_k<<<1, 512, 0, stream>>>(bsum, NB);
    block_scan_write_k<<<NB, 256, 0, stream>>>(cnt, bsum, off, N, E);
    fill_k<<<blks(E), 256, 0, stream>>>(src, dst, ev, rank, off, edges, E);

    // ---- layer 1: (x @ W1) -> pull(+b1, leaky) ----  [aggregate in 16]
    gemm_rows<512, 16, 0><<<blks(N), 256, 0, stream>>>(x, W1, nullptr, sup, N);
    pull16<1><<<pull_blocks, 256, 0, stream>>>(off, edges, sup, b1, h, N);

    // ---- layer 2: pull(h) -> @ W2 (+b2, leaky) ----  [aggregate in 16, then 16->64]
    pull16<0><<<pull_blocks, 256, 0, stream>>>(off, edges, h, nullptr, sup, N);
    gemm_rows<16, 64, 1><<<blks(N), 256, 0, stream>>>(sup, W2, b2, h, N);

    // ---- layer 3: (h @ W3) -> pull(+b3) -> log_softmax ----
    gemm_rows<64, 16, 0><<<blks(N), 256, 0, stream>>>(h, W3, nullptr, sup, N);
    pull16<2><<<pull_blocks, 256, 0, stream>>>(off, edges, sup, b3, out, N);
}

// Round 4
// 529.295 us; speedup vs baseline: 30.1693x; 1.2754x over previous
//
#include <hip/hip_runtime.h>
#include <cmath>

// GCN: 3 x (dense GEMM <-> pull-SpMM) + fused log_softmax.
// Build: ONE pass direct placement into fixed-capacity per-node buckets
// (CAP=64, mean degree 32) with an exact overflow fallback list. gemm1 is
// fused into the same launch (disjoint block range) to hide under atomic
// latency. Algebra: spmm(A, h@W) == spmm(A, h)@W -> always aggregate in 16.
// Layer-1 activation is recomputed inside layer-2's gather so pulls always
// produce raw sums (overflow adds stay correct).

#define CAP 64
#define OVF_CAP 262144

// ---------------- fused: gemm1 (x@W1 -> t1) + edge placement --------------
__global__ __launch_bounds__(256) void build_k(const float* __restrict__ x,
                                               const float* __restrict__ W1,
                                               float* __restrict__ t1,
                                               const int* __restrict__ src,
                                               const int* __restrict__ dst,
                                               const float* __restrict__ ev,
                                               int* __restrict__ cnt,
                                               int2* __restrict__ edges,
                                               int* __restrict__ ovfcnt,
                                               int4* __restrict__ ovf,
                                               int N, int E, int NB_gemm) {
    if ((int)blockIdx.x < NB_gemm) {
        int row = blockIdx.x * 256 + threadIdx.x;
        if (row >= N) return;
        float acc[16];
#pragma unroll
        for (int c = 0; c < 16; ++c) acc[c] = 0.f;
        const float4* Xv = reinterpret_cast<const float4*>(x + (size_t)row * 512);
        for (int k0 = 0; k0 < 512; k0 += 4) {
            float4 xv = Xv[k0 / 4];
            const float xs[4] = {xv.x, xv.y, xv.z, xv.w};
#pragma unroll
            for (int kk = 0; kk < 4; ++kk)
#pragma unroll
                for (int c = 0; c < 16; ++c)
                    acc[c] += xs[kk] * W1[(size_t)(k0 + kk) * 16 + c];
        }
        float4* Yv = reinterpret_cast<float4*>(t1 + (size_t)row * 16);
#pragma unroll
        for (int q = 0; q < 4; ++q)
            Yv[q] = make_float4(acc[4*q], acc[4*q+1], acc[4*q+2], acc[4*q+3]);
    } else {
        int e = ((int)blockIdx.x - NB_gemm) * 256 + threadIdx.x;
        if (e >= E) return;
        int d = dst[e];
        int p = atomicAdd(&cnt[d], 1);
        if (p < CAP) {
            edges[(size_t)d * CAP + p] = make_int2(src[e], __float_as_int(ev[e]));
        } else {
            int o = atomicAdd(ovfcnt, 1);
            if (o < OVF_CAP) ovf[o] = make_int4(src[e], d, __float_as_int(ev[e]), 0);
        }
    }
}

// ---------------- pull-SpMM: wave/node, 4 edge-groups x 16 features -------
// ACT=1: gathered value is leaky(S[src]+b) (recompute layer activation).
template<int ACT>
__global__ __launch_bounds__(256) void pull_cap(const int* __restrict__ cnt,
                                                const int2* __restrict__ edges,
                                                const float* __restrict__ S,
                                                const float* __restrict__ b,
                                                float* __restrict__ O, int N) {
    int wid = (blockIdx.x * 256 + (int)threadIdx.x) >> 6;
    int lane = threadIdx.x & 63;
    if (wid >= N) return;
    int c = lane & 15, eg = lane >> 4;
    int deg = cnt[wid];
    deg = deg < CAP ? deg : CAP;
    const int2* ep = edges + (size_t)wid * CAP;
    float bc = ACT ? b[c] : 0.f;
    float acc = 0.f;
    for (int e = eg; e < deg; e += 4) {
        int2 ed = ep[e];
        float sx = S[(size_t)ed.x * 16 + c];
        if (ACT) {
            sx += bc;
            sx = sx > 0.f ? sx : 0.01f * sx;
        }
        acc += __int_as_float(ed.y) * sx;
    }
    acc += __shfl_xor(acc, 16);
    acc += __shfl_xor(acc, 32);
    if (lane < 16) O[(size_t)wid * 16 + c] = acc;
}

// ---------------- overflow edges: exact fallback (usually 0 edges) --------
template<int ACT>
__global__ __launch_bounds__(256) void ovf_k(const int* __restrict__ ovfcnt,
                                             const int4* __restrict__ ovf,
                                             const float* __restrict__ S,
                                             const float* __restrict__ b,
                                             float* __restrict__ O) {
    int K = *ovfcnt;
    K = K < OVF_CAP ? K : OVF_CAP;
    for (int i = blockIdx.x * 256 + threadIdx.x; i < K * 16; i += gridDim.x * 256) {
        int e = i >> 4, c = i & 15;
        int4 r = ovf[e];
        float sx = S[(size_t)r.x * 16 + c];
        if (ACT) {
            sx += b[c];
            sx = sx > 0.f ? sx : 0.01f * sx;
        }
        atomicAdd(&O[(size_t)r.y * 16 + c], __int_as_float(r.z) * sx);
    }
}

// ---------------- fused gemm2+leaky+gemm3: t3 = leaky(a2@W2+b2)@W3 --------
__global__ __launch_bounds__(256) void gemm23_k(const float* __restrict__ A,
                                                const float* __restrict__ W2,
                                                const float* __restrict__ b2,
                                                const float* __restrict__ W3,
                                                float* __restrict__ T3, int N) {
    int row = blockIdx.x * 256 + threadIdx.x;
    if (row >= N) return;
    float a[16];
    const float4* Av = reinterpret_cast<const float4*>(A + (size_t)row * 16);
#pragma unroll
    for (int q = 0; q < 4; ++q) {
        float4 t = Av[q];
        a[4*q] = t.x; a[4*q+1] = t.y; a[4*q+2] = t.z; a[4*q+3] = t.w;
    }
    float h[64];
#pragma unroll
    for (int j = 0; j < 64; ++j) h[j] = b2[j];
#pragma unroll
    for (int k = 0; k < 16; ++k)
#pragma unroll
        for (int j = 0; j < 64; ++j)
            h[j] += a[k] * W2[(size_t)k * 64 + j];
#pragma unroll
    for (int j = 0; j < 64; ++j) h[j] = h[j] > 0.f ? h[j] : 0.01f * h[j];
    float o[16];
#pragma unroll
    for (int c = 0; c < 16; ++c) o[c] = 0.f;
#pragma unroll
    for (int j = 0; j < 64; ++j)
#pragma unroll
        for (int c = 0; c < 16; ++c)
            o[c] += h[j] * W3[(size_t)j * 16 + c];
    float4* Yv = reinterpret_cast<float4*>(T3 + (size_t)row * 16);
#pragma unroll
    for (int q = 0; q < 4; ++q)
        Yv[q] = make_float4(o[4*q], o[4*q+1], o[4*q+2], o[4*q+3]);
}

// ---------------- out = log_softmax(a3 + b3) ------------------------------
__global__ __launch_bounds__(256) void lsm_k(const float* __restrict__ A,
                                             const float* __restrict__ b3,
                                             float* __restrict__ out, int N) {
    int row = blockIdx.x * 256 + threadIdx.x;
    if (row >= N) return;
    float v[16];
    const float4* Av = reinterpret_cast<const float4*>(A + (size_t)row * 16);
#pragma unroll
    for (int q = 0; q < 4; ++q) {
        float4 t = Av[q];
        v[4*q] = t.x; v[4*q+1] = t.y; v[4*q+2] = t.z; v[4*q+3] = t.w;
    }
#pragma unroll
    for (int c = 0; c < 16; ++c) v[c] += b3[c];
    float m = v[0];
#pragma unroll
    for (int c = 1; c < 16; ++c) m = fmaxf(m, v[c]);
    float ssum = 0.f;
#pragma unroll
    for (int c = 0; c < 16; ++c) ssum += __expf(v[c] - m);
    float lse = m + __logf(ssum);
    float4* Ov = reinterpret_cast<float4*>(out + (size_t)row * 16);
#pragma unroll
    for (int q = 0; q < 4; ++q)
        Ov[q] = make_float4(v[4*q] - lse, v[4*q+1] - lse, v[4*q+2] - lse, v[4*q+3] - lse);
}

extern "C" void kernel_launch(void* const* d_in, const int* in_sizes, int n_in,
                              void* d_out, int out_size, void* d_ws, size_t ws_size,
                              hipStream_t stream) {
    const float* x   = (const float*)d_in[0];
    const int*   src = (const int*)d_in[1];
    const int*   dst = (const int*)d_in[2];
    const float* ev  = (const float*)d_in[3];
    const float* W1  = (const float*)d_in[4];
    const float* b1  = (const float*)d_in[5];
    const float* W2  = (const float*)d_in[6];
    const float* b2  = (const float*)d_in[7];
    const float* W3  = (const float*)d_in[8];
    const float* b3  = (const float*)d_in[9];
    float* out = (float*)d_out;

    const int N = in_sizes[0] / 512;   // 100000
    const int E = in_sizes[1];         // 3200000

    // workspace layout (4B units)
    float* B0    = (float*)d_ws;                    // N x 16
    float* B1    = B0 + (size_t)N * 16;             // N x 16
    float* B2    = B1 + (size_t)N * 16;             // N x 16
    int2*  edges = (int2*)(B2 + (size_t)N * 16);    // N x CAP packed {src, ev}
    int*   cnt   = (int*)(edges + (size_t)N * CAP); // N
    int*   ovfc  = cnt + N;                         // 1
    // align overflow list to 16B
    int4*  ovf   = (int4*)(((uintptr_t)(ovfc + 1) + 15) & ~(uintptr_t)15);

    auto blks = [](long n) { return (int)((n + 255) / 256); };
    const int NB_gemm = blks(N);                    // 391
    const int NB_place = blks(E);                   // 12500
    const int pull_blocks = blks((long)N * 64);     // 1 wave per node

    // zero cnt + ovfcnt (adjacent) in one memset
    hipMemsetAsync(cnt, 0, (size_t)(N + 1) * 4, stream);

    // ---- build: t1 = x@W1 fused with edge placement ----
    build_k<<<NB_gemm + NB_place, 256, 0, stream>>>(x, W1, B0, src, dst, ev,
                                                    cnt, edges, ovfc, ovf,
                                                    N, E, NB_gemm);

    // ---- layer 1 aggregate: a1 = spmm(t1) (raw) ----
    pull_cap<0><<<pull_blocks, 256, 0, stream>>>(cnt, edges, B0, nullptr, B1, N);
    ovf_k<0><<<64, 256, 0, stream>>>(ovfc, ovf, B0, nullptr, B1);

    // ---- layer 2 aggregate: a2 = spmm(leaky(a1+b1)) (act on gather) ----
    pull_cap<1><<<pull_blocks, 256, 0, stream>>>(cnt, edges, B1, b1, B2, N);
    ovf_k<1><<<64, 256, 0, stream>>>(ovfc, ovf, B1, b1, B2);

    // ---- t3 = leaky(a2@W2+b2)@W3 (register-resident row kernel) ----
    gemm23_k<<<NB_gemm, 256, 0, stream>>>(B2, W2, b2, W3, B0, N);

    // ---- layer 3 aggregate: a3 = spmm(t3) (raw) ----
    pull_cap<0><<<pull_blocks, 256, 0, stream>>>(cnt, edges, B0, nullptr, B1, N);
    ovf_k<0><<<64, 256, 0, stream>>>(ovfc, ovf, B0, nullptr, B1);

    // ---- out = log_softmax(a3 + b3) ----
    lsm_k<<<NB_gemm, 256, 0, stream>>>(B1, b3, out, N);
}